// Round 1
// baseline (1248.711 us; speedup 1.0000x reference)
//
#include <hip/hip_runtime.h>
#include <math.h>

#define B_N 16
#define C_N 128
#define CM_N 64
#define H_N 128
#define W_N 128
#define HW_N (H_N * W_N)

// ---------------------------------------------------------------------------
// Stage 1: q[b][c][w] = mean_h relu(bn(Wq x)), vT[b][w][c] = mean_h relu(bn(Wv x))
// grid (16, 32) : b x h-slab(4), block 384 threads. 8x8 register tile per thread
// over a 192(o) x 128(w) output slab; H-mean accumulated in registers across
// the 4 h values, then ONE atomicAdd per output element per block.
// ---------------------------------------------------------------------------
__global__ __launch_bounds__(384) void qv_kernel(
    const float* __restrict__ x,
    const float* __restrict__ Wq, const float* __restrict__ sq, const float* __restrict__ bq,
    const float* __restrict__ Wv, const float* __restrict__ sv, const float* __restrict__ bv,
    float* __restrict__ qbuf, float* __restrict__ vTbuf)
{
    __shared__ float Xc[32][128];   // 16 KB : K-chunk of x (c x w)
    __shared__ float Wc[32][192];   // 24 KB : K-chunk of [Wq;Wv]^T (kk x o)

    const int b   = blockIdx.x;
    const int h0  = blockIdx.y * 4;
    const int tid = threadIdx.x;
    const int o0  = (tid >> 4) * 8;   // 24 o-groups -> 0..184
    const int w0  = (tid & 15) * 8;   // 16 w-groups -> 0..120

    // hoist BN params for this thread's 8 output rows
    float bns[8], bnb[8];
#pragma unroll
    for (int j = 0; j < 8; ++j) {
        int o = o0 + j;
        if (o < CM_N) { bns[j] = sq[o];        bnb[j] = bq[o]; }
        else          { bns[j] = sv[o - CM_N]; bnb[j] = bv[o - CM_N]; }
    }

    float hacc[8][8];
#pragma unroll
    for (int j = 0; j < 8; ++j)
#pragma unroll
        for (int l = 0; l < 8; ++l) hacc[j][l] = 0.f;

    for (int h = h0; h < h0 + 4; ++h) {
        float acc[8][8];
#pragma unroll
        for (int j = 0; j < 8; ++j)
#pragma unroll
            for (int l = 0; l < 8; ++l) acc[j][l] = 0.f;

        for (int kc = 0; kc < 4; ++kc) {
            __syncthreads();
            // load X chunk: rows c = kc*32 + r, 128 w each (coalesced float4)
            for (int idx = tid; idx < 1024; idx += 384) {
                int r = idx >> 5, c4 = (idx & 31) << 2;
                *(float4*)&Xc[r][c4] =
                    *(const float4*)(x + (((size_t)(b * C_N + kc * 32 + r)) * H_N + h) * W_N + c4);
            }
            // load W chunk transposed (kk x o); scattered but L1/L2-resident
            for (int idx = tid; idx < 6144; idx += 384) {
                int kk = idx / 192, o = idx - kk * 192;
                Wc[kk][o] = (o < CM_N) ? Wq[o * C_N + kc * 32 + kk]
                                       : Wv[(o - CM_N) * C_N + kc * 32 + kk];
            }
            __syncthreads();
#pragma unroll
            for (int kk = 0; kk < 32; ++kk) {
                float a[8], bb[8];
#pragma unroll
                for (int j = 0; j < 8; ++j) a[j] = Wc[kk][o0 + j];
#pragma unroll
                for (int l = 0; l < 8; ++l) bb[l] = Xc[kk][w0 + l];
#pragma unroll
                for (int j = 0; j < 8; ++j)
#pragma unroll
                    for (int l = 0; l < 8; ++l)
                        acc[j][l] = fmaf(a[j], bb[l], acc[j][l]);
            }
        }
        // BN + ReLU for this h, accumulate mean
#pragma unroll
        for (int j = 0; j < 8; ++j)
#pragma unroll
            for (int l = 0; l < 8; ++l)
                hacc[j][l] += fmaxf(fmaf(acc[j][l], bns[j], bnb[j]), 0.f);
    }

    const float inv = 1.0f / (float)H_N;
#pragma unroll
    for (int j = 0; j < 8; ++j) {
        int o = o0 + j;
        if (o < CM_N) {
#pragma unroll
            for (int l = 0; l < 8; ++l)
                atomicAdd(&qbuf[((size_t)b * CM_N + o) * W_N + w0 + l], hacc[j][l] * inv);
        } else {
            int c = o - CM_N;
#pragma unroll
            for (int l = 0; l < 8; ++l)
                atomicAdd(&vTbuf[((size_t)b * W_N + w0 + l) * C_N + c], hacc[j][l] * inv);
        }
    }
}

// ---------------------------------------------------------------------------
// Stage 2: fused  K-conv -> S = q^T K -> column softmax (over w) -> Aug = V A'
//          -> out = x + Aug/denom.   grid (128 n-tiles, 16 b), block 256.
// LDS (142 KB, unioned):
//   [0      ..32768)  Klds  64x128            | vTlds 128x128 (phase C)
//   [32768  ..65536)  qlds  64x128            |
//   [65536  ..133120) Slds 128x132 (padded, 16B-aligned rows)
//   [133120 ..145408) Xc 16x128 + Wkc 16x64   | pmax/psum/cmax/rden (softmax)
// ---------------------------------------------------------------------------
__global__ __launch_bounds__(256) void attn_kernel(
    const float* __restrict__ x,
    const float* __restrict__ Wk, const float* __restrict__ sk, const float* __restrict__ bk,
    const float* __restrict__ qbuf, const float* __restrict__ vTbuf,
    float* __restrict__ out)
{
    __shared__ __align__(16) char smem[145408];
    float (*Klds)[128]  = (float (*)[128])(smem);
    float (*qlds)[128]  = (float (*)[128])(smem + 32768);
    float (*vTlds)[128] = (float (*)[128])(smem);            // union with Klds+qlds
    float (*Slds)[132]  = (float (*)[132])(smem + 65536);
    float (*Xc)[128]    = (float (*)[128])(smem + 133120);
    float (*Wkc)[64]    = (float (*)[64])(smem + 141312);
    float* pmax = (float*)(smem + 133120);   // union with Xc (dead after phase A)
    float* psum = pmax + 256;
    float* cmax = psum + 256;
    float* rden = cmax + 128;

    const int nt  = blockIdx.x;
    const int b   = blockIdx.y;
    const int tid = threadIdx.x;
    const size_t xoff = (size_t)b * C_N * HW_N + (size_t)nt * W_N;
    const int n0 = (tid & 15) * 8;

    // ---- Phase A: Klds = relu(bn(Wk @ Xtile)), 64 x 128, K=128 chunked by 16
    {
        const int oa0 = (tid >> 4) * 4;
        float acc[4][8];
#pragma unroll
        for (int j = 0; j < 4; ++j)
#pragma unroll
            for (int l = 0; l < 8; ++l) acc[j][l] = 0.f;

        for (int kc = 0; kc < 8; ++kc) {
            __syncthreads();
            for (int idx = tid; idx < 512; idx += 256) {
                int r = idx >> 5, c4 = (idx & 31) << 2;
                *(float4*)&Xc[r][c4] =
                    *(const float4*)(x + xoff + (size_t)(kc * 16 + r) * HW_N + c4);
            }
            for (int idx = tid; idx < 1024; idx += 256) {
                int kk = idx >> 6, o = idx & 63;
                Wkc[kk][o] = Wk[o * C_N + kc * 16 + kk];
            }
            __syncthreads();
#pragma unroll
            for (int kk = 0; kk < 16; ++kk) {
                float a[4], bb[8];
#pragma unroll
                for (int j = 0; j < 4; ++j) a[j] = Wkc[kk][oa0 + j];
#pragma unroll
                for (int l = 0; l < 8; ++l) bb[l] = Xc[kk][n0 + l];
#pragma unroll
                for (int j = 0; j < 4; ++j)
#pragma unroll
                    for (int l = 0; l < 8; ++l)
                        acc[j][l] = fmaf(a[j], bb[l], acc[j][l]);
            }
        }
#pragma unroll
        for (int j = 0; j < 4; ++j) {
            int o = oa0 + j;
            float s = sk[o], bi = bk[o];
#pragma unroll
            for (int l = 0; l < 8; ++l)
                Klds[o][n0 + l] = fmaxf(fmaf(acc[j][l], s, bi), 0.f);
        }
    }

    // ---- load q[b] into LDS (contiguous 32 KB)
    {
        const float4* src = (const float4*)(qbuf + (size_t)b * CM_N * W_N);
        for (int idx = tid; idx < 2048; idx += 256)
            ((float4*)qlds)[idx] = src[idx];
    }
    __syncthreads();

    // ---- Phase B: S[w][n] = sum_c q[c][w] * K[c][n]
    {
        const int w0 = (tid >> 4) * 8;
        float acc[8][8];
#pragma unroll
        for (int j = 0; j < 8; ++j)
#pragma unroll
            for (int l = 0; l < 8; ++l) acc[j][l] = 0.f;
#pragma unroll
        for (int kk = 0; kk < 64; ++kk) {
            float a[8], bb[8];
#pragma unroll
            for (int j = 0; j < 8; ++j) a[j] = qlds[kk][w0 + j];
#pragma unroll
            for (int l = 0; l < 8; ++l) bb[l] = Klds[kk][n0 + l];
#pragma unroll
            for (int j = 0; j < 8; ++j)
#pragma unroll
                for (int l = 0; l < 8; ++l)
                    acc[j][l] = fmaf(a[j], bb[l], acc[j][l]);
        }
#pragma unroll
        for (int j = 0; j < 8; ++j) {
            *(float4*)&Slds[w0 + j][n0]     = make_float4(acc[j][0], acc[j][1], acc[j][2], acc[j][3]);
            *(float4*)&Slds[w0 + j][n0 + 4] = make_float4(acc[j][4], acc[j][5], acc[j][6], acc[j][7]);
        }
    }
    __syncthreads();

    // ---- column softmax over w (denominator deferred to epilogue)
    {
        int n = tid & 127, half = tid >> 7;
        float m = -1e30f;
        for (int w = half * 64; w < half * 64 + 64; ++w) m = fmaxf(m, Slds[w][n]);
        pmax[half * 128 + n] = m;
    }
    __syncthreads();
    if (tid < 128) cmax[tid] = fmaxf(pmax[tid], pmax[128 + tid]);
    __syncthreads();
    for (int idx = tid; idx < 16384; idx += 256) {
        int w = idx >> 7, n = idx & 127;
        Slds[w][n] = __expf(Slds[w][n] - cmax[n]);
    }
    __syncthreads();
    {
        int n = tid & 127, half = tid >> 7;
        float s = 0.f;
        for (int w = half * 64; w < half * 64 + 64; ++w) s += Slds[w][n];
        psum[half * 128 + n] = s;
    }
    __syncthreads();
    if (tid < 128) rden[tid] = 1.0f / (psum[tid] + psum[128 + tid]);
    __syncthreads();

    // ---- Phase C: load vT[b] (overwrites Klds/qlds), Aug GEMM, residual epilogue
    {
        const float4* src = (const float4*)(vTbuf + (size_t)b * W_N * C_N);
        for (int idx = tid; idx < 4096; idx += 256)
            ((float4*)vTlds)[idx] = src[idx];
    }
    __syncthreads();
    {
        const int c0 = (tid >> 4) * 8;
        float acc[8][8];
#pragma unroll
        for (int j = 0; j < 8; ++j)
#pragma unroll
            for (int l = 0; l < 8; ++l) acc[j][l] = 0.f;
#pragma unroll
        for (int kk = 0; kk < 128; ++kk) {
            float a[8], bb[8];
#pragma unroll
            for (int j = 0; j < 8; ++j) a[j] = vTlds[kk][c0 + j];
#pragma unroll
            for (int l = 0; l < 8; ++l) bb[l] = Slds[kk][n0 + l];
#pragma unroll
            for (int j = 0; j < 8; ++j)
#pragma unroll
                for (int l = 0; l < 8; ++l)
                    acc[j][l] = fmaf(a[j], bb[l], acc[j][l]);
        }
        float rd[8];
#pragma unroll
        for (int l = 0; l < 8; ++l) rd[l] = rden[n0 + l];
#pragma unroll
        for (int j = 0; j < 8; ++j) {
            const float* xp = x   + xoff + (size_t)(c0 + j) * HW_N + n0;
            float*       op = out + xoff + (size_t)(c0 + j) * HW_N + n0;
            float4 x0 = *(const float4*)xp;
            float4 x1 = *(const float4*)(xp + 4);
            float4 r0, r1;
            r0.x = x0.x + acc[j][0] * rd[0];
            r0.y = x0.y + acc[j][1] * rd[1];
            r0.z = x0.z + acc[j][2] * rd[2];
            r0.w = x0.w + acc[j][3] * rd[3];
            r1.x = x1.x + acc[j][4] * rd[4];
            r1.y = x1.y + acc[j][5] * rd[5];
            r1.z = x1.z + acc[j][6] * rd[6];
            r1.w = x1.w + acc[j][7] * rd[7];
            *(float4*)op       = r0;
            *(float4*)(op + 4) = r1;
        }
    }
}

extern "C" void kernel_launch(void* const* d_in, const int* in_sizes, int n_in,
                              void* d_out, int out_size, void* d_ws, size_t ws_size,
                              hipStream_t stream)
{
    const float* x  = (const float*)d_in[0];
    const float* Wq = (const float*)d_in[1];
    const float* sq = (const float*)d_in[2];
    const float* bq = (const float*)d_in[3];
    const float* Wk = (const float*)d_in[4];
    const float* sk = (const float*)d_in[5];
    const float* bk = (const float*)d_in[6];
    const float* Wv = (const float*)d_in[7];
    const float* sv = (const float*)d_in[8];
    const float* bv = (const float*)d_in[9];
    float* outp = (float*)d_out;

    float* qbuf  = (float*)d_ws;                       // 16*64*128  floats
    float* vTbuf = qbuf + (size_t)B_N * CM_N * W_N;    // 16*128*128 floats

    const size_t accum_bytes = ((size_t)B_N * CM_N * W_N + (size_t)B_N * W_N * C_N) * sizeof(float);
    hipMemsetAsync(d_ws, 0, accum_bytes, stream);

    qv_kernel<<<dim3(16, 32), 384, 0, stream>>>(x, Wq, sq, bq, Wv, sv, bv, qbuf, vTbuf);
    attn_kernel<<<dim3(128, 16), 256, 0, stream>>>(x, Wk, sk, bk, qbuf, vTbuf, outp);
}

// Round 4
// 743.373 us; speedup vs baseline: 1.6798x; 1.6798x over previous
//
#include <hip/hip_runtime.h>
#include <math.h>

#define B_N 16
#define C_N 128
#define CM_N 64
#define H_N 128
#define W_N 128
#define HW_N (H_N * W_N)

// ---------------------------------------------------------------------------
// Kernel 0: pre-transpose weights into ws so all later staging is float4.
//   WTqv[c][o] (128x192): o<64 -> Wq[o][c], else Wv[o-64][c]
//   WTk [c][o] (128x64)
// ---------------------------------------------------------------------------
__global__ __launch_bounds__(512) void transpose_w_kernel(
    const float* __restrict__ Wq, const float* __restrict__ Wv, const float* __restrict__ Wk,
    float* __restrict__ WTqv, float* __restrict__ WTk)
{
    int idx = blockIdx.x * 512 + threadIdx.x;
    if (idx < 128 * 192) {
        int c = idx / 192, o = idx - c * 192;
        WTqv[idx] = (o < CM_N) ? Wq[o * C_N + c] : Wv[(o - CM_N) * C_N + c];
    } else {
        int i2 = idx - 128 * 192;
        if (i2 < 128 * 64) {
            int c = i2 >> 6, o = i2 & 63;
            WTk[i2] = Wk[o * C_N + c];
        }
    }
}

// ---------------------------------------------------------------------------
// Kernel 1: conv(q,v)+BN+ReLU, partial h-sum over a 4-h slab.
// grid (16 b, 32 hslab) x 384 thr. Per thread: 8(o) x 8(w as two float4 at
// w0/w0+64) register tile. NO atomics: partials -> d_out scratch
// [slab][b][o192][w128].
// ---------------------------------------------------------------------------
__global__ __launch_bounds__(384) void qv_kernel(
    const float* __restrict__ x, const float* __restrict__ WTqv,
    const float* __restrict__ sq, const float* __restrict__ bq,
    const float* __restrict__ sv, const float* __restrict__ bv,
    float* __restrict__ partials)
{
    __shared__ float Xc[32][128];   // 16 KB
    __shared__ float Wc[32][192];   // 24 KB

    const int b  = blockIdx.x;
    const int hs = blockIdx.y;
    const int tid = threadIdx.x;
    const int o0 = (tid >> 4) * 8;   // 24 groups
    const int w0 = (tid & 15) * 4;   // two float4: w0, w0+64

    float bns[8], bnb[8];
#pragma unroll
    for (int j = 0; j < 8; ++j) {
        int o = o0 + j;
        if (o < CM_N) { bns[j] = sq[o];         bnb[j] = bq[o]; }
        else          { bns[j] = sv[o - CM_N];  bnb[j] = bv[o - CM_N]; }
    }

    float hacc[8][8];
#pragma unroll
    for (int j = 0; j < 8; ++j)
#pragma unroll
        for (int l = 0; l < 8; ++l) hacc[j][l] = 0.f;

    for (int h = hs * 4; h < hs * 4 + 4; ++h) {
        float acc[8][8];
#pragma unroll
        for (int j = 0; j < 8; ++j)
#pragma unroll
            for (int l = 0; l < 8; ++l) acc[j][l] = 0.f;

        for (int kc = 0; kc < 4; ++kc) {
            __syncthreads();
            for (int i = tid; i < 1024; i += 384) {
                int r = i >> 5, c4 = (i & 31) << 2;
                *(float4*)&Xc[r][c4] =
                    *(const float4*)(x + (((size_t)(b * C_N + kc * 32 + r)) * H_N + h) * W_N + c4);
            }
            for (int i = tid; i < 1536; i += 384) {
                int r = i / 48, o4 = (i - r * 48) << 2;
                *(float4*)&Wc[r][o4] = *(const float4*)(WTqv + (kc * 32 + r) * 192 + o4);
            }
            __syncthreads();
#pragma unroll 8
            for (int kk = 0; kk < 32; ++kk) {
                float a[8], xv[8];
                *(float4*)&a[0]  = *(float4*)&Wc[kk][o0];
                *(float4*)&a[4]  = *(float4*)&Wc[kk][o0 + 4];
                *(float4*)&xv[0] = *(float4*)&Xc[kk][w0];
                *(float4*)&xv[4] = *(float4*)&Xc[kk][w0 + 64];
#pragma unroll
                for (int j = 0; j < 8; ++j)
#pragma unroll
                    for (int l = 0; l < 8; ++l)
                        acc[j][l] = fmaf(a[j], xv[l], acc[j][l]);
            }
        }
#pragma unroll
        for (int j = 0; j < 8; ++j)
#pragma unroll
            for (int l = 0; l < 8; ++l)
                hacc[j][l] += fmaxf(fmaf(acc[j][l], bns[j], bnb[j]), 0.f);
    }

#pragma unroll
    for (int j = 0; j < 8; ++j) {
        float* p = partials + (((size_t)hs * 16 + b) * 192 + (o0 + j)) * 128;
        *(float4*)(p + w0)      = make_float4(hacc[j][0], hacc[j][1], hacc[j][2], hacc[j][3]);
        *(float4*)(p + w0 + 64) = make_float4(hacc[j][4], hacc[j][5], hacc[j][6], hacc[j][7]);
    }
}

// ---------------------------------------------------------------------------
// Kernel 2: sum 32 partial slabs -> qbuf[b][o][w] (o<64), vTbuf[b][w][c] (o>=64)
// ---------------------------------------------------------------------------
__global__ __launch_bounds__(512) void reduce_kernel(
    const float* __restrict__ partials, float* __restrict__ qbuf, float* __restrict__ vTbuf)
{
    int idx = blockIdx.x * 512 + threadIdx.x;   // < 16*192*128 = 393216
    int w = idx & 127;
    int t = idx >> 7;
    int o = t % 192;
    int b = t / 192;
    float s = 0.f;
#pragma unroll 8
    for (int sl = 0; sl < 32; ++sl)
        s += partials[(size_t)sl * 393216 + idx];
    s *= (1.0f / 128.0f);
    if (o < CM_N) qbuf[((size_t)b * CM_N + o) * W_N + w] = s;
    else          vTbuf[((size_t)b * W_N + w) * C_N + (o - CM_N)] = s;
}

// ---------------------------------------------------------------------------
// Kernel 3: fused  K-conv -> S=q^T K -> softmax over w -> Aug=V P -> out=x+Aug
// grid (128 n-tiles, 16 b) x 512 thr (8 waves).
// LDS 138240 B:
//   [0     ..32768 ) Klds 64x128    | vTlds 128x128 (phase C)
//   [32768 ..65536 ) qlds 64x128    |
//   [65536 ..133120) Slds 128x132   | phase-A staging Xc 32x128 + Wkc 32x64
//   [133120..138240) softmax scratch pmax/psum[4][128], cmax/rden[128]
// ---------------------------------------------------------------------------
__global__ __launch_bounds__(512) void attn_kernel(
    const float* __restrict__ x, const float* __restrict__ WTk,
    const float* __restrict__ sk, const float* __restrict__ bk,
    const float* __restrict__ qbuf, const float* __restrict__ vTbuf,
    float* __restrict__ out)
{
    __shared__ __align__(16) char smem[138240];
    float (*Klds)[128]  = (float (*)[128])(smem);
    float (*qlds)[128]  = (float (*)[128])(smem + 32768);
    float (*vTlds)[128] = (float (*)[128])(smem);
    float (*Slds)[132]  = (float (*)[132])(smem + 65536);
    float (*Xc)[128]    = (float (*)[128])(smem + 65536);          // phase A only
    float (*Wkc)[64]    = (float (*)[64])(smem + 65536 + 16384);   // phase A only
    float* pmax = (float*)(smem + 133120);
    float* psum = pmax + 512;
    float* cmax = psum + 512;
    float* rden = cmax + 128;

    const int nt  = blockIdx.x;
    const int b   = blockIdx.y;
    const int tid = threadIdx.x;
    const size_t xoff = (size_t)b * C_N * HW_N + (size_t)nt * W_N;

    // ---- Phase A: Klds[64][128] = relu(bn(Wk @ Xtile))
    {
        const int o0 = (tid >> 4) * 2;   // 32 groups * 2 = 64
        const int w0 = (tid & 15) * 4;
        float acc[2][8];
#pragma unroll
        for (int j = 0; j < 2; ++j)
#pragma unroll
            for (int l = 0; l < 8; ++l) acc[j][l] = 0.f;

        for (int kc = 0; kc < 4; ++kc) {
            __syncthreads();
            for (int i = tid; i < 1024; i += 512) {
                int r = i >> 5, c4 = (i & 31) << 2;
                *(float4*)&Xc[r][c4] =
                    *(const float4*)(x + xoff + (size_t)(kc * 32 + r) * HW_N + c4);
            }
            {
                int r = tid >> 4, o4 = (tid & 15) << 2;
                *(float4*)&Wkc[r][o4] = *(const float4*)(WTk + (kc * 32 + r) * 64 + o4);
            }
            __syncthreads();
#pragma unroll 8
            for (int kk = 0; kk < 32; ++kk) {
                float a0 = Wkc[kk][o0], a1 = Wkc[kk][o0 + 1];
                float xv[8];
                *(float4*)&xv[0] = *(float4*)&Xc[kk][w0];
                *(float4*)&xv[4] = *(float4*)&Xc[kk][w0 + 64];
#pragma unroll
                for (int l = 0; l < 8; ++l) {
                    acc[0][l] = fmaf(a0, xv[l], acc[0][l]);
                    acc[1][l] = fmaf(a1, xv[l], acc[1][l]);
                }
            }
        }
        float s0 = sk[o0], bi0 = bk[o0], s1 = sk[o0 + 1], bi1 = bk[o0 + 1];
        *(float4*)&Klds[o0][w0] = make_float4(
            fmaxf(fmaf(acc[0][0], s0, bi0), 0.f), fmaxf(fmaf(acc[0][1], s0, bi0), 0.f),
            fmaxf(fmaf(acc[0][2], s0, bi0), 0.f), fmaxf(fmaf(acc[0][3], s0, bi0), 0.f));
        *(float4*)&Klds[o0][w0 + 64] = make_float4(
            fmaxf(fmaf(acc[0][4], s0, bi0), 0.f), fmaxf(fmaf(acc[0][5], s0, bi0), 0.f),
            fmaxf(fmaf(acc[0][6], s0, bi0), 0.f), fmaxf(fmaf(acc[0][7], s0, bi0), 0.f));
        *(float4*)&Klds[o0 + 1][w0] = make_float4(
            fmaxf(fmaf(acc[1][0], s1, bi1), 0.f), fmaxf(fmaf(acc[1][1], s1, bi1), 0.f),
            fmaxf(fmaf(acc[1][2], s1, bi1), 0.f), fmaxf(fmaf(acc[1][3], s1, bi1), 0.f));
        *(float4*)&Klds[o0 + 1][w0 + 64] = make_float4(
            fmaxf(fmaf(acc[1][4], s1, bi1), 0.f), fmaxf(fmaf(acc[1][5], s1, bi1), 0.f),
            fmaxf(fmaf(acc[1][6], s1, bi1), 0.f), fmaxf(fmaf(acc[1][7], s1, bi1), 0.f));
    }

    // ---- load q[b] (32 KB, contiguous)
    {
        const float4* src = (const float4*)(qbuf + (size_t)b * CM_N * W_N);
        for (int i = tid; i < 2048; i += 512)
            ((float4*)qlds)[i] = src[i];
    }
    __syncthreads();

    // ---- Phase B: S[w][n] = sum_c q[c][w] K[c][n]
    {
        const int w0 = (tid >> 4) * 4;   // 32 groups * 4 = 128
        const int n0 = (tid & 15) * 4;   // two float4: n0, n0+64
        float acc[4][8];
#pragma unroll
        for (int j = 0; j < 4; ++j)
#pragma unroll
            for (int l = 0; l < 8; ++l) acc[j][l] = 0.f;
#pragma unroll 8
        for (int kk = 0; kk < 64; ++kk) {
            float a[4], bb[8];
            *(float4*)&a[0]  = *(float4*)&qlds[kk][w0];
            *(float4*)&bb[0] = *(float4*)&Klds[kk][n0];
            *(float4*)&bb[4] = *(float4*)&Klds[kk][n0 + 64];
#pragma unroll
            for (int j = 0; j < 4; ++j)
#pragma unroll
                for (int l = 0; l < 8; ++l)
                    acc[j][l] = fmaf(a[j], bb[l], acc[j][l]);
        }
#pragma unroll
        for (int j = 0; j < 4; ++j) {
            *(float4*)&Slds[w0 + j][n0]      = make_float4(acc[j][0], acc[j][1], acc[j][2], acc[j][3]);
            *(float4*)&Slds[w0 + j][n0 + 64] = make_float4(acc[j][4], acc[j][5], acc[j][6], acc[j][7]);
        }
    }
    __syncthreads();

    // ---- vT global loads issued early (written to LDS after exp pass)
    float4 vreg[8];
    {
        const float4* src = (const float4*)(vTbuf + (size_t)b * W_N * C_N);
#pragma unroll
        for (int i = 0; i < 8; ++i) vreg[i] = src[tid + 512 * i];
    }

    // ---- softmax over w (4 threads per column)
    {
        int n = tid & 127, qu = tid >> 7;
        float m = -1e30f;
        for (int w = qu * 32; w < qu * 32 + 32; ++w) m = fmaxf(m, Slds[w][n]);
        pmax[qu * 128 + n] = m;
    }
    __syncthreads();
    if (tid < 128)
        cmax[tid] = fmaxf(fmaxf(pmax[tid], pmax[128 + tid]),
                          fmaxf(pmax[256 + tid], pmax[384 + tid]));
    __syncthreads();
    for (int i = tid; i < 4096; i += 512) {
        int w = i >> 5, nq = (i & 31) << 2;
        float4 v  = *(float4*)&Slds[w][nq];
        float4 cm = *(const float4*)&cmax[nq];
        v.x = __expf(v.x - cm.x); v.y = __expf(v.y - cm.y);
        v.z = __expf(v.z - cm.z); v.w = __expf(v.w - cm.w);
        *(float4*)&Slds[w][nq] = v;
    }
    // write vT into LDS (Klds/qlds region is dead now)
    {
        float4* dst = (float4*)vTlds;
#pragma unroll
        for (int i = 0; i < 8; ++i) dst[tid + 512 * i] = vreg[i];
    }
    __syncthreads();
    {
        int n = tid & 127, qu = tid >> 7;
        float s = 0.f;
        for (int w = qu * 32; w < qu * 32 + 32; ++w) s += Slds[w][n];
        psum[qu * 128 + n] = s;
    }
    __syncthreads();
    if (tid < 128)
        rden[tid] = 1.0f / (psum[tid] + psum[128 + tid] + psum[256 + tid] + psum[384 + tid]);
    __syncthreads();

    // ---- Phase C: Aug[c][n] = sum_w vT[w][c] * P[w][n]; out = x + Aug*rden
    {
        const int c0 = (tid >> 4) * 4;   // 32 groups * 4 = 128
        const int n0 = (tid & 15) * 4;
        float acc[4][8];
#pragma unroll
        for (int j = 0; j < 4; ++j)
#pragma unroll
            for (int l = 0; l < 8; ++l) acc[j][l] = 0.f;
#pragma unroll 8
        for (int kk = 0; kk < 128; ++kk) {
            float a[4], bb[8];
            *(float4*)&a[0]  = *(float4*)&vTlds[kk][c0];
            *(float4*)&bb[0] = *(float4*)&Slds[kk][n0];
            *(float4*)&bb[4] = *(float4*)&Slds[kk][n0 + 64];
#pragma unroll
            for (int j = 0; j < 4; ++j)
#pragma unroll
                for (int l = 0; l < 8; ++l)
                    acc[j][l] = fmaf(a[j], bb[l], acc[j][l]);
        }
        float rd[8];
        *(float4*)&rd[0] = *(const float4*)&rden[n0];
        *(float4*)&rd[4] = *(const float4*)&rden[n0 + 64];
#pragma unroll
        for (int j = 0; j < 4; ++j) {
            const float* xp = x   + xoff + (size_t)(c0 + j) * HW_N;
            float*       op = out + xoff + (size_t)(c0 + j) * HW_N;
            float4 x0 = *(const float4*)(xp + n0);
            float4 x1 = *(const float4*)(xp + n0 + 64);
            float4 r0, r1;
            r0.x = x0.x + acc[j][0] * rd[0];
            r0.y = x0.y + acc[j][1] * rd[1];
            r0.z = x0.z + acc[j][2] * rd[2];
            r0.w = x0.w + acc[j][3] * rd[3];
            r1.x = x1.x + acc[j][4] * rd[4];
            r1.y = x1.y + acc[j][5] * rd[5];
            r1.z = x1.z + acc[j][6] * rd[6];
            r1.w = x1.w + acc[j][7] * rd[7];
            *(float4*)(op + n0)      = r0;
            *(float4*)(op + n0 + 64) = r1;
        }
    }
}

extern "C" void kernel_launch(void* const* d_in, const int* in_sizes, int n_in,
                              void* d_out, int out_size, void* d_ws, size_t ws_size,
                              hipStream_t stream)
{
    const float* x  = (const float*)d_in[0];
    const float* Wq = (const float*)d_in[1];
    const float* sq = (const float*)d_in[2];
    const float* bq = (const float*)d_in[3];
    const float* Wk = (const float*)d_in[4];
    const float* sk = (const float*)d_in[5];
    const float* bk = (const float*)d_in[6];
    const float* Wv = (const float*)d_in[7];
    const float* sv = (const float*)d_in[8];
    const float* bv = (const float*)d_in[9];
    float* outp = (float*)d_out;

    float* WTqv  = (float*)d_ws;                       // 128*192
    float* WTk   = WTqv + 128 * 192;                   // 128*64
    float* qbuf  = WTk + 128 * 64;                     // 16*64*128
    float* vTbuf = qbuf + (size_t)B_N * CM_N * W_N;    // 16*128*128

    // qv partials live in d_out scratch: [32][16][192][128] = 50.3 MB < 128 MB,
    // fully overwritten afterwards by attn_kernel's complete output write.
    float* partials = outp;

    transpose_w_kernel<<<64, 512, 0, stream>>>(Wq, Wv, Wk, WTqv, WTk);
    qv_kernel<<<dim3(16, 32), 384, 0, stream>>>(x, WTqv, sq, bq, sv, bv, partials);
    reduce_kernel<<<768, 512, 0, stream>>>(partials, qbuf, vTbuf);
    attn_kernel<<<dim3(128, 16), 512, 0, stream>>>(x, WTk, sk, bk, qbuf, vTbuf, outp);
}

// Round 5
// 370.242 us; speedup vs baseline: 3.3727x; 2.0078x over previous
//
#include <hip/hip_runtime.h>
#include <math.h>

#define B_N 16
#define C_N 128
#define CM_N 64
#define H_N 128
#define W_N 128
#define HW_N (H_N * W_N)

typedef float  f32x4  __attribute__((ext_vector_type(4)));
typedef short  s16x8  __attribute__((ext_vector_type(8)));

#define MFMA_BF16(a, b, c) __builtin_amdgcn_mfma_f32_16x16x32_bf16((a), (b), (c), 0, 0, 0)

// fp32 -> bf16 round-to-nearest-even
static __device__ inline unsigned short f2bf(float f) {
    union { float f; unsigned u; } v; v.f = f;
    unsigned r = v.u + 0x7fffu + ((v.u >> 16) & 1u);
    return (unsigned short)(r >> 16);
}

// ---------------------------------------------------------------------------
// Fragment-linear ("frag-packed") layouts. For an MxK A-operand (or NxK
// B-operand) tiled 16x32: tile t = mt*KT + kt. Lane l of the reading wave does
// ds_read_b128 at (t*512 + l*8) ushorts and receives elements
// [row = mt*16 + (l&15)][k = kt*32 + (l>>4)*8 + j], j=0..7.
// ---------------------------------------------------------------------------

// ---------------------------------------------------------------------------
// Kernel 0: pack weights into frag-linear bf16.
//  WqvA: A-op of [Wq;Wv]  (M=192 o, K=128 c) -> 48 tiles
//  WkA : A-op of Wk       (M=64  o, K=128 c) -> 16 tiles
// ---------------------------------------------------------------------------
__global__ __launch_bounds__(512) void prep_w_kernel(
    const float* __restrict__ Wq, const float* __restrict__ Wv, const float* __restrict__ Wk,
    unsigned short* __restrict__ WqvA, unsigned short* __restrict__ WkA)
{
    int t = blockIdx.x * 512 + threadIdx.x;
    int lane = t & 63, tile = t >> 6;
    if (tile < 48) {
        int mt = tile >> 2, kt = tile & 3;
        int m = mt * 16 + (lane & 15);
        int k0 = kt * 32 + ((lane >> 4) << 3);
        const float* src = (m < CM_N) ? (Wq + m * C_N + k0) : (Wv + (m - CM_N) * C_N + k0);
        unsigned short* dst = WqvA + tile * 512 + lane * 8;
#pragma unroll
        for (int j = 0; j < 8; ++j) dst[j] = f2bf(src[j]);
    } else if (tile < 64) {
        int tt = tile - 48;
        int mt = tt >> 2, kt = tt & 3;
        int m = mt * 16 + (lane & 15);
        int k0 = kt * 32 + ((lane >> 4) << 3);
        const float* src = Wk + m * C_N + k0;
        unsigned short* dst = WkA + tt * 512 + lane * 8;
#pragma unroll
        for (int j = 0; j < 8; ++j) dst[j] = f2bf(src[j]);
    }
}

// ---------------------------------------------------------------------------
// Kernel 1: qv conv via MFMA. grid (16 b, 16 hslab8, 2 whalf) x 512 thr.
// Per block: 192 o x 64 w, 8 h values; BN+ReLU per h; h-partial sum -> d_out
// scratch in D-frag-linear float4 order (perfectly coalesced).
// LDS: WqvA copy 48 KB + X B-frag 16 KB = 64 KB -> 2 blocks/CU.
// ---------------------------------------------------------------------------
__global__ __launch_bounds__(512, 4) void qv_kernel(
    const float* __restrict__ x, const unsigned short* __restrict__ WqvA,
    const float* __restrict__ sq, const float* __restrict__ bq,
    const float* __restrict__ sv, const float* __restrict__ bv,
    float* __restrict__ partials)
{
    __shared__ __align__(16) unsigned short Wl[24576];  // 48 tiles
    __shared__ __align__(16) unsigned short Xf[8192];   // 16 tiles (4 ntL x 4 ct)

    const int b = blockIdx.x, hs = blockIdx.y, wh = blockIdx.z;
    const int tid = threadIdx.x, lane = tid & 63, wid = tid >> 6;
    const int mw = wid >> 1, nw = wid & 1;   // 4 x 2 wave grid

    for (int i = tid; i < 3072; i += 512)
        ((ulonglong2*)Wl)[i] = ((const ulonglong2*)WqvA)[i];

    // BN params for this thread's 12 output rows (3 Mt x 4 regs)
    float sArr[12], bArr[12];
#pragma unroll
    for (int m = 0; m < 3; ++m)
#pragma unroll
        for (int r = 0; r < 4; ++r) {
            int o = (mw * 3 + m) * 16 + ((lane >> 4) << 2) + r;
            if (o < CM_N) { sArr[m * 4 + r] = sq[o];          bArr[m * 4 + r] = bq[o]; }
            else          { sArr[m * 4 + r] = sv[o - CM_N];   bArr[m * 4 + r] = bv[o - CM_N]; }
        }

    f32x4 hacc[3][2];
#pragma unroll
    for (int m = 0; m < 3; ++m)
#pragma unroll
        for (int n = 0; n < 2; ++n) hacc[m][n] = (f32x4)0.f;

    for (int h = hs * 8; h < hs * 8 + 8; ++h) {
        __syncthreads();   // protect Xf from prior-iteration readers
        // stage X B-frag: 2 tiles per wave; in-register transpose
#pragma unroll
        for (int i = 0; i < 2; ++i) {
            int t = wid * 2 + i;
            int ntL = t >> 2, ct = t & 3;
            int n = wh * 64 + ntL * 16 + (lane & 15);
            int c0 = ct * 32 + ((lane >> 4) << 3);
            const float* xp = x + (((size_t)(b * C_N + c0)) * H_N + h) * W_N + n;
            s16x8 v;
#pragma unroll
            for (int j = 0; j < 8; ++j) v[j] = (short)f2bf(xp[(size_t)j * HW_N]);
            *(s16x8*)(Xf + t * 512 + lane * 8) = v;
        }
        __syncthreads();

        f32x4 acc[3][2];
#pragma unroll
        for (int m = 0; m < 3; ++m)
#pragma unroll
            for (int n = 0; n < 2; ++n) acc[m][n] = (f32x4)0.f;

#pragma unroll
        for (int kt = 0; kt < 4; ++kt) {
            s16x8 aW[3], bX[2];
#pragma unroll
            for (int m = 0; m < 3; ++m)
                aW[m] = *(const s16x8*)(Wl + ((mw * 3 + m) * 4 + kt) * 512 + lane * 8);
#pragma unroll
            for (int n = 0; n < 2; ++n)
                bX[n] = *(const s16x8*)(Xf + ((nw * 2 + n) * 4 + kt) * 512 + lane * 8);
#pragma unroll
            for (int m = 0; m < 3; ++m)
#pragma unroll
                for (int n = 0; n < 2; ++n)
                    acc[m][n] = MFMA_BF16(aW[m], bX[n], acc[m][n]);
        }
        // BN + ReLU, accumulate over h
#pragma unroll
        for (int m = 0; m < 3; ++m)
#pragma unroll
            for (int n = 0; n < 2; ++n)
#pragma unroll
                for (int r = 0; r < 4; ++r)
                    hacc[m][n][r] += fmaxf(fmaf(acc[m][n][r], sArr[m * 4 + r], bArr[m * 4 + r]), 0.f);
    }

    // write partials (D-frag-linear, float4 per tile per lane)
    const int slab = hs * 16 + b;
#pragma unroll
    for (int m = 0; m < 3; ++m)
#pragma unroll
        for (int n = 0; n < 2; ++n) {
            int tile = (mw * 3 + m) * 4 + (nw * 2 + n);
            float4 v4;
            v4.x = hacc[m][n][0] * (1.f / 128.f);
            v4.y = hacc[m][n][1] * (1.f / 128.f);
            v4.z = hacc[m][n][2] * (1.f / 128.f);
            v4.w = hacc[m][n][3] * (1.f / 128.f);
            *(float4*)(partials + ((size_t)((slab * 2 + wh) * 48 + tile)) * 256 + lane * 4) = v4;
        }
}

// ---------------------------------------------------------------------------
// Kernel 2: sum 16 h-slabs; emit qA (A-frag of q: M=128 w, K=64 c) and
// vA (A-frag of V: M=128 c, K=128 w) as bf16.
// ---------------------------------------------------------------------------
__global__ __launch_bounds__(512) void reduce_kernel(
    const float* __restrict__ partials,
    unsigned short* __restrict__ qA, unsigned short* __restrict__ vA)
{
    int idx = blockIdx.x * 512 + threadIdx.x;     // < 393216
    float s = 0.f;
#pragma unroll 4
    for (int hsl = 0; hsl < 16; ++hsl)
        s += partials[(size_t)hsl * 393216 + idx];

    int b   = idx / 24576;  int r0 = idx - b * 24576;
    int wh  = r0 / 12288;   int r1 = r0 - wh * 12288;
    int tile = r1 >> 8;     int r2 = r1 & 255;
    int lane = r2 >> 2;     int reg = r2 & 3;
    int Mt = tile >> 2, NtL = tile & 3;
    int o = Mt * 16 + ((lane >> 4) << 2) + reg;
    int w = wh * 64 + NtL * 16 + (lane & 15);
    unsigned short hv = f2bf(s);
    if (o < CM_N) {
        qA[(size_t)b * 8192 + ((w >> 4) * 2 + (o >> 5)) * 512
           + ((w & 15) + ((o >> 3) & 3) * 16) * 8 + (o & 7)] = hv;
    } else {
        int c = o - CM_N;
        vA[(size_t)b * 16384 + ((c >> 4) * 4 + (w >> 5)) * 512
           + ((c & 15) + ((w >> 3) & 3) * 16) * 8 + (w & 7)] = hv;
    }
}

// ---------------------------------------------------------------------------
// Kernel 3: fused K-conv -> S=q^T K -> softmax(w) -> Aug=V E -> out=x+Aug/den.
// grid (128 n-tiles, 16 b) x 512 thr (8 waves). All GEMMs on MFMA.
// LDS 147456 B:
//  [0     , 32768) XB (phase-A B-frag)      | VA (phase-C A-frag)
//  [32768 , 49152) WkA copy | qA copy | softmax scratch (pmax/psum/cmax/rden)
//  [49152 ,114688) S fp32 [128][128]
//  [114688,147456) KB (A-out B-frag, 16 KB) | EB (E B-frag, 32 KB)
// ---------------------------------------------------------------------------
__global__ __launch_bounds__(512) void attn_kernel(
    const float* __restrict__ x,
    const unsigned short* __restrict__ WkA,
    const unsigned short* __restrict__ qAg, const unsigned short* __restrict__ vAg,
    const float* __restrict__ sk, const float* __restrict__ bk,
    float* __restrict__ out)
{
    __shared__ __align__(16) char smem[147456];
    unsigned short* XB  = (unsigned short*)smem;             // 16384 us
    unsigned short* VA  = (unsigned short*)smem;             // 16384 us (after XB dead)
    unsigned short* WkL = (unsigned short*)(smem + 32768);   // 8192 us
    unsigned short* qL  = (unsigned short*)(smem + 32768);   // 8192 us (after WkL dead)
    float* scr          = (float*)(smem + 32768);            // (after qL dead)
    float (*S)[128]     = (float (*)[128])(smem + 49152);
    unsigned short* KB  = (unsigned short*)(smem + 114688);  // 8192 us
    unsigned short* EB  = (unsigned short*)(smem + 114688);  // 16384 us (after KB dead)
    float* pmax = scr;          // 512
    float* psum = scr + 512;    // 512
    float* cmax = scr + 1024;   // 128
    float* rden = scr + 1152;   // 128

    const int ntb = blockIdx.x, b = blockIdx.y;
    const int tid = threadIdx.x, lane = tid & 63, wid = tid >> 6;
    const size_t xoff = (size_t)b * C_N * HW_N + (size_t)ntb * W_N;

    // copy WkA -> LDS
    for (int i = tid; i < 1024; i += 512)
        ((ulonglong2*)WkL)[i] = ((const ulonglong2*)WkA)[i];

    // stage X B-frag (32 tiles, 4 per wave) with in-register transpose
#pragma unroll
    for (int i = 0; i < 4; ++i) {
        int t = wid * 4 + i;
        int nt = t >> 2, ct = t & 3;
        int n = nt * 16 + (lane & 15);
        int c0 = ct * 32 + ((lane >> 4) << 3);
        const float* xp = x + xoff + (size_t)c0 * HW_N + n;
        s16x8 v;
#pragma unroll
        for (int j = 0; j < 8; ++j) v[j] = (short)f2bf(xp[(size_t)j * HW_N]);
        *(s16x8*)(XB + t * 512 + lane * 8) = v;
    }
    __syncthreads();

    // ---- Phase A: K-conv (64 x 128), BN+ReLU, pack to KB (B-frag, K=o)
    {
        const int mw = wid >> 2, nw2 = wid & 3;
        f32x4 accA[2][2];
#pragma unroll
        for (int m = 0; m < 2; ++m)
#pragma unroll
            for (int n = 0; n < 2; ++n) accA[m][n] = (f32x4)0.f;
#pragma unroll
        for (int kt = 0; kt < 4; ++kt) {
            s16x8 aK[2], bX[2];
#pragma unroll
            for (int m = 0; m < 2; ++m)
                aK[m] = *(const s16x8*)(WkL + ((mw * 2 + m) * 4 + kt) * 512 + lane * 8);
#pragma unroll
            for (int n = 0; n < 2; ++n)
                bX[n] = *(const s16x8*)(XB + ((nw2 * 2 + n) * 4 + kt) * 512 + lane * 8);
#pragma unroll
            for (int m = 0; m < 2; ++m)
#pragma unroll
                for (int n = 0; n < 2; ++n)
                    accA[m][n] = MFMA_BF16(aK[m], bX[n], accA[m][n]);
        }
#pragma unroll
        for (int m = 0; m < 2; ++m) {
            int Mt = mw * 2 + m;
#pragma unroll
            for (int rp = 0; rp < 2; ++rp) {
                int o0 = Mt * 16 + ((lane >> 4) << 2) + rp * 2;
                float s0 = sk[o0], bi0 = bk[o0], s1 = sk[o0 + 1], bi1 = bk[o0 + 1];
#pragma unroll
                for (int n = 0; n < 2; ++n) {
                    int Nt = nw2 * 2 + n;
                    float v0 = fmaxf(fmaf(accA[m][n][rp * 2],     s0, bi0), 0.f);
                    float v1 = fmaxf(fmaf(accA[m][n][rp * 2 + 1], s1, bi1), 0.f);
                    unsigned pack = (unsigned)f2bf(v0) | ((unsigned)f2bf(v1) << 16);
                    *(unsigned*)(KB + (Nt * 2 + (o0 >> 5)) * 512
                                 + ((lane & 15) + ((o0 >> 3) & 3) * 16) * 8 + (o0 & 7)) = pack;
                }
            }
        }
    }
    __syncthreads();   // KB ready; WkL/XB dead

    // load qA and vA (frag-packed) into LDS
    for (int i = tid; i < 1024; i += 512)
        ((ulonglong2*)qL)[i] = ((const ulonglong2*)(qAg + (size_t)b * 8192))[i];
    for (int i = tid; i < 2048; i += 512)
        ((ulonglong2*)VA)[i] = ((const ulonglong2*)(vAg + (size_t)b * 16384))[i];
    __syncthreads();

    // ---- Phase B: S[w][n] = q^T K   (wave = 16 w-rows; all 128 n)
    {
        f32x4 acc8[8];
#pragma unroll
        for (int n = 0; n < 8; ++n) acc8[n] = (f32x4)0.f;
#pragma unroll
        for (int kt = 0; kt < 2; ++kt) {
            s16x8 aq = *(const s16x8*)(qL + (wid * 2 + kt) * 512 + lane * 8);
#pragma unroll
            for (int n = 0; n < 8; ++n) {
                s16x8 bK = *(const s16x8*)(KB + (n * 2 + kt) * 512 + lane * 8);
                acc8[n] = MFMA_BF16(aq, bK, acc8[n]);
            }
        }
        int w0 = wid * 16 + ((lane >> 4) << 2);
#pragma unroll
        for (int n = 0; n < 8; ++n)
#pragma unroll
            for (int r = 0; r < 4; ++r)
                S[w0 + r][n * 16 + (lane & 15)] = acc8[n][r];
    }
    __syncthreads();   // S ready; qL dead -> scr usable

    // ---- softmax over w (max pass)
    {
        int n = tid & 127, qu = tid >> 7;
        float m = -1e30f;
        for (int w = qu * 32; w < qu * 32 + 32; ++w) m = fmaxf(m, S[w][n]);
        pmax[qu * 128 + n] = m;
    }
    __syncthreads();
    if (tid < 128)
        cmax[tid] = fmaxf(fmaxf(pmax[tid], pmax[128 + tid]),
                          fmaxf(pmax[256 + tid], pmax[384 + tid]));
    __syncthreads();

    // ---- exp pass: write fp32 back to S (for psum) and bf16 to EB (frag)
#pragma unroll
    for (int p = 0; p < 4; ++p) {
        int w = (tid >> 4) + p * 32;
        int nq = (tid & 15) * 8;
        float4 a = *(float4*)&S[w][nq];
        float4 bb = *(float4*)&S[w][nq + 4];
        float4 c0 = *(const float4*)&cmax[nq];
        float4 c1 = *(const float4*)&cmax[nq + 4];
        float e[8];
        e[0] = __expf(a.x - c0.x); e[1] = __expf(a.y - c0.y);
        e[2] = __expf(a.z - c0.z); e[3] = __expf(a.w - c0.w);
        e[4] = __expf(bb.x - c1.x); e[5] = __expf(bb.y - c1.y);
        e[6] = __expf(bb.z - c1.z); e[7] = __expf(bb.w - c1.w);
        *(float4*)&S[w][nq]     = make_float4(e[0], e[1], e[2], e[3]);
        *(float4*)&S[w][nq + 4] = make_float4(e[4], e[5], e[6], e[7]);
        unsigned short* eb = EB + ((w >> 5) << 9) + (w & 7);   // + (n>>4)*2048 + lane_e*8
#pragma unroll
        for (int j = 0; j < 8; ++j) {
            int n = nq + j;
            eb[((n >> 4) * 4) * 512 + ((n & 15) + ((w >> 3) & 3) * 16) * 8] = f2bf(e[j]);
        }
    }
    __syncthreads();

    // ---- sum pass -> rden
    {
        int n = tid & 127, qu = tid >> 7;
        float s = 0.f;
        for (int w = qu * 32; w < qu * 32 + 32; ++w) s += S[w][n];
        psum[qu * 128 + n] = s;
    }
    __syncthreads();
    if (tid < 128)
        rden[tid] = 1.0f / (psum[tid] + psum[128 + tid] + psum[256 + tid] + psum[384 + tid]);
    __syncthreads();

    // ---- Phase C: Aug[c][n] = V * E  (wave = 16 c-rows; all 128 n)
    {
        f32x4 accC[8];
#pragma unroll
        for (int n = 0; n < 8; ++n) accC[n] = (f32x4)0.f;
#pragma unroll
        for (int kt = 0; kt < 4; ++kt) {
            s16x8 aV = *(const s16x8*)(VA + (wid * 4 + kt) * 512 + lane * 8);
#pragma unroll
            for (int n = 0; n < 8; ++n) {
                s16x8 bE = *(const s16x8*)(EB + (n * 4 + kt) * 512 + lane * 8);
                accC[n] = MFMA_BF16(aV, bE, accC[n]);
            }
        }
        int c0 = wid * 16 + ((lane >> 4) << 2);
#pragma unroll
        for (int n = 0; n < 8; ++n) {
            int ncol = n * 16 + (lane & 15);
            float rd = rden[ncol];
#pragma unroll
            for (int r = 0; r < 4; ++r) {
                size_t off = xoff + (size_t)(c0 + r) * HW_N + ncol;
                out[off] = x[off] + accC[n][r] * rd;
            }
        }
    }
}

extern "C" void kernel_launch(void* const* d_in, const int* in_sizes, int n_in,
                              void* d_out, int out_size, void* d_ws, size_t ws_size,
                              hipStream_t stream)
{
    const float* x  = (const float*)d_in[0];
    const float* Wq = (const float*)d_in[1];
    const float* sq = (const float*)d_in[2];
    const float* bq = (const float*)d_in[3];
    const float* Wk = (const float*)d_in[4];
    const float* sk = (const float*)d_in[5];
    const float* bk = (const float*)d_in[6];
    const float* Wv = (const float*)d_in[7];
    const float* sv = (const float*)d_in[8];
    const float* bv = (const float*)d_in[9];
    float* outp = (float*)d_out;

    unsigned short* wsu  = (unsigned short*)d_ws;
    unsigned short* WqvA = wsu;                  // 24576 us
    unsigned short* WkA  = wsu + 24576;          // 8192  us
    unsigned short* qA   = wsu + 32768;          // 16*8192 us
    unsigned short* vA   = wsu + 163840;         // 16*16384 us  (total ~832 KB)

    // qv partials in d_out scratch: 16slabs*16b*2wh*48tiles*256 floats = 25.2 MB,
    // fully overwritten later by attn_kernel's complete output.
    float* partials = outp;

    prep_w_kernel<<<8, 512, 0, stream>>>(Wq, Wv, Wk, WqvA, WkA);
    qv_kernel<<<dim3(16, 16, 2), 512, 0, stream>>>(x, WqvA, sq, bq, sv, bv, partials);
    reduce_kernel<<<768, 512, 0, stream>>>(partials, qA, vA);
    attn_kernel<<<dim3(128, 16), 512, 0, stream>>>(x, WkA, qA, vA, sk, bk, outp);
}